// Round 13
// baseline (154.085 us; speedup 1.0000x reference)
//
#include <hip/hip_runtime.h>

#define E_ 56
#define DIM_ 512
#define V_ 256
#define F_ 504       // E_*9
#define NROWS 65536  // B*L

typedef float  vf4 __attribute__((ext_vector_type(4)));
typedef unsigned int vu4 __attribute__((ext_vector_type(4)));

__device__ __forceinline__ float sigmoidf_(float v) { return 1.0f / (1.0f + expf(-v)); }
__device__ __forceinline__ float bf_lo_(unsigned int u) {
  return __uint_as_float(u << 16);
}
__device__ __forceinline__ float bf_hi_(unsigned int u) {
  return __uint_as_float(u & 0xFFFF0000u);
}
__device__ __forceinline__ float bf2f_(unsigned short u) {
  return __uint_as_float(((unsigned int)u) << 16);
}
__device__ __forceinline__ unsigned short f2bf_(float f) {  // round-nearest-even
  unsigned int b = __float_as_uint(f);
  b += 0x7FFFu + ((b >> 16) & 1u);
  return (unsigned short)(b >> 16);
}

// ---- fused: transposes + beff ---------------------------------------------
__global__ __launch_bounds__(256) void k_pre(
    const float* __restrict__ proj_w,   // [512][504]
    const float* __restrict__ conv_w,   // [56][504]
    const float* __restrict__ conv_b,   // [56]
    const float* __restrict__ proj_b,   // [512]
    const float* __restrict__ alpha,    // [9]
    float* __restrict__ PW2,            // [9][512][56]
    float* __restrict__ Ct,             // [56][9][56]
    float* __restrict__ beff)           // [512]
{
  int b = blockIdx.x;
  if (b < 1008) {
    int idx = b * 256 + threadIdx.x;
    int p = idx / (DIM_ * E_);
    int r = idx - p * (DIM_ * E_);
    int d = r / E_;
    int e = r - d * E_;
    PW2[idx] = proj_w[d * F_ + e * 9 + p];
  } else if (b < 1119) {
    int j = (b - 1008) * 256 + threadIdx.x;
    if (j < E_ * 9 * E_) {              // 28224
      int c = j / (9 * E_);
      int r = j - c * (9 * E_);
      int k = r / E_;
      int e = r - k * E_;
      Ct[j] = conv_w[e * F_ + c * 9 + k];
    }
  } else {
    int d = (b - 1119) * 4 + (threadIdx.x >> 6);
    int lane = threadIdx.x & 63;
    const float* pr = proj_w + d * F_;
    float acc = 0.f;
    #pragma unroll
    for (int p = 0; p < 9; ++p) {
      float v = 0.f;
      if (lane < E_) v = pr[lane * 9 + p] * conv_b[lane];
      #pragma unroll
      for (int off = 32; off > 0; off >>= 1) v += __shfl_xor(v, off, 64);
      acc += (1.f - sigmoidf_(alpha[p])) * v;
    }
    if (lane == 0) beff[d] = proj_b[d] + acc;
  }
}

// ---- Weff fold (R6-proven; 1008 blocks keeps the GPU saturated) -----------
__global__ __launch_bounds__(256) void k_weff2(
    const float* __restrict__ proj_w,   // [512][504]
    const float* __restrict__ PW2,      // [9][512][56]
    const float* __restrict__ Ct,       // [56][9][56]
    const float* __restrict__ alpha,    // [9]
    float* __restrict__ Wt)             // [9][56][512] f32
{
  int idx = blockIdx.x * 256 + threadIdx.x;   // 512*504 threads
  int d = idx / F_;
  int f = idx - d * F_;
  int c = f / 9;
  int q = f - c * 9;
  int qi = q / 3, qj = q - qi * 3;
  float acc = sigmoidf_(alpha[q]) * proj_w[d * F_ + c * 9 + q];
  #pragma unroll
  for (int p = 0; p < 9; ++p) {
    int pi = p / 3, pj = p - pi * 3;
    int ki = qi - pi + 1, kj = qj - pj + 1;
    if (ki < 0 || ki > 2 || kj < 0 || kj > 2) continue;
    const vf4* A = (const vf4*)(PW2 + (p * DIM_ + d) * E_);
    const vf4* B = (const vf4*)(Ct + (c * 9 + (ki * 3 + kj)) * E_);
    vf4 sv = {0.f, 0.f, 0.f, 0.f};
    #pragma unroll
    for (int e4 = 0; e4 < E_ / 4; ++e4)
      sv += A[e4] * B[e4];
    float s = sv.x + sv.y + sv.z + sv.w;
    acc += (1.f - sigmoidf_(alpha[p])) * s;
  }
  Wt[(size_t)(q * E_ + c) * DIM_ + d] = acc;
}

// T[q][t][d] = beff[d]/9 + sum_c emb[t][c] * Wt[q][c][d]   (bias folded)
__global__ __launch_bounds__(256) void k_tab8b(
    const float* __restrict__ emb,      // [256][56]
    const float* __restrict__ Wt,       // [9][56][512] f32
    const float* __restrict__ beff,     // [512]
    unsigned short* __restrict__ T)     // [9][256][512] bf16
{
  int q  = blockIdx.x >> 5;
  int t0 = (blockIdx.x & 31) * 8;
  int d0 = 2 * threadIdx.x;
  const float inv9 = 1.0f / 9.0f;
  float2 bv = *(const float2*)(beff + d0);
  float b0 = bv.x * inv9, b1 = bv.y * inv9;
  float a0[8], a1[8];
  #pragma unroll
  for (int j = 0; j < 8; ++j) { a0[j] = b0; a1[j] = b1; }
  for (int c = 0; c < E_; ++c) {
    float2 w = *(const float2*)(Wt + (size_t)(q * E_ + c) * DIM_ + d0);
    #pragma unroll
    for (int j = 0; j < 8; ++j) {
      float ev = emb[(t0 + j) * E_ + c];   // uniform -> scalar load
      a0[j] += ev * w.x;
      a1[j] += ev * w.y;
    }
  }
  #pragma unroll
  for (int j = 0; j < 8; ++j) {
    size_t o = (size_t)((q << 8) + t0 + j) * DIM_ + d0;
    unsigned int u = (unsigned int)f2bf_(a0[j]) | ((unsigned int)f2bf_(a1[j]) << 16);
    *(unsigned int*)(T + o) = u;
  }
}

// Shared LayerNorm tail helper ----------------------------------------------
__device__ __forceinline__ void ln_reduce_(const float a[8], float& mu, float& rstd) {
  float s = 0.f, ss = 0.f;
  #pragma unroll
  for (int j = 0; j < 8; ++j) { s += a[j]; ss += a[j] * a[j]; }
  #pragma unroll
  for (int off = 32; off > 0; off >>= 1) {
    s  += __shfl_xor(s, off, 64);
    ss += __shfl_xor(ss, off, 64);
  }
  mu = s * (1.0f / 512.0f);
  float var = ss * (1.0f / 512.0f) - mu * mu;
  rstd = rsqrtf(var + 1e-5f);
}

// 4 rows per wave, 2-deep gather pipeline; gamma/beta hoisted per wave.
// T gathers are NONTEMPORAL: random 2.36MB table -> ~0% L1 hit rate, so
// bypass L1 allocation (stream from L2) and leave L1 to the store path.
__global__ __launch_bounds__(256) void k_main4c(
    const int*            __restrict__ x,     // [65536][9]
    const unsigned short* __restrict__ T,     // [9][256][512] bf16 (biased)
    const float* __restrict__ gamma,
    const float* __restrict__ beta,
    float* __restrict__ out)                  // [65536][512]
{
  int lane = threadIdx.x & 63;
  int wid  = __builtin_amdgcn_readfirstlane(threadIdx.x >> 6);
  int row0 = blockIdx.x * 16 + wid * 4;       // grid = NROWS/16
  const int* __restrict__ xr = x + row0 * 9;  // uniform -> s_load

  const float4* g4  = (const float4*)gamma;
  const float4* be4 = (const float4*)beta;
  float4 G0 = g4[2 * lane],  G1 = g4[2 * lane + 1];
  float4 P0 = be4[2 * lane], P1 = be4[2 * lane + 1];

  vu4 cur[9], nxt[9];
  #pragma unroll
  for (int q = 0; q < 9; ++q)
    cur[q] = __builtin_nontemporal_load(
        (const vu4*)(T + (size_t)((q << 8) + xr[q]) * DIM_) + lane);

  #pragma unroll
  for (int r = 0; r < 4; ++r) {
    if (r < 3) {
      #pragma unroll
      for (int q = 0; q < 9; ++q)
        nxt[q] = __builtin_nontemporal_load(
            (const vu4*)(T + (size_t)((q << 8) + xr[(r + 1) * 9 + q]) * DIM_) + lane);
    }

    float a[8] = {0.f, 0.f, 0.f, 0.f, 0.f, 0.f, 0.f, 0.f};
    #pragma unroll
    for (int q = 0; q < 9; ++q) {
      a[0] += bf_lo_(cur[q].x); a[1] += bf_hi_(cur[q].x);
      a[2] += bf_lo_(cur[q].y); a[3] += bf_hi_(cur[q].y);
      a[4] += bf_lo_(cur[q].z); a[5] += bf_hi_(cur[q].z);
      a[6] += bf_lo_(cur[q].w); a[7] += bf_hi_(cur[q].w);
    }

    float mu, rstd;
    ln_reduce_(a, mu, rstd);

    vf4 o0, o1;
    o0.x = (a[0] - mu) * rstd * G0.x + P0.x;
    o0.y = (a[1] - mu) * rstd * G0.y + P0.y;
    o0.z = (a[2] - mu) * rstd * G0.z + P0.z;
    o0.w = (a[3] - mu) * rstd * G0.w + P0.w;
    o1.x = (a[4] - mu) * rstd * G1.x + P1.x;
    o1.y = (a[5] - mu) * rstd * G1.y + P1.y;
    o1.z = (a[6] - mu) * rstd * G1.z + P1.z;
    o1.w = (a[7] - mu) * rstd * G1.w + P1.w;

    vf4* o4 = (vf4*)(out + (size_t)(row0 + r) * DIM_ + lane * 8);
    __builtin_nontemporal_store(o0, o4);
    __builtin_nontemporal_store(o1, o4 + 1);

    if (r < 3) {
      #pragma unroll
      for (int q = 0; q < 9; ++q) cur[q] = nxt[q];
    }
  }
}

// ----------------- tiny-ws fallback ----------------------------------------
__global__ __launch_bounds__(256) void k_weff_bf(
    const float* __restrict__ proj_w,
    const float* __restrict__ conv_w,
    const float* __restrict__ alpha,
    unsigned short* __restrict__ Wt)
{
  int idx = blockIdx.x * 256 + threadIdx.x;
  int d = idx / F_;
  int f = idx - d * F_;
  int c = f / 9;
  int q = f - c * 9;
  int qi = q / 3, qj = q - qi * 3;
  const float* pr = proj_w + d * F_;
  float acc = sigmoidf_(alpha[q]) * pr[c * 9 + q];
  for (int pi = 0; pi < 3; ++pi) {
    for (int pj = 0; pj < 3; ++pj) {
      int ki = qi - pi + 1, kj = qj - pj + 1;
      if (ki < 0 || ki > 2 || kj < 0 || kj > 2) continue;
      int p = pi * 3 + pj;
      const float* cwp = conv_w + c * 9 + (ki * 3 + kj);
      const float* prp = pr + p;
      float s = 0.f;
      #pragma unroll 8
      for (int e = 0; e < E_; ++e)
        s += prp[e * 9] * cwp[e * F_];
      acc += (1.f - sigmoidf_(alpha[p])) * s;
    }
  }
  Wt[(size_t)(q * E_ + c) * DIM_ + d] = f2bf_(acc);
}

__global__ __launch_bounds__(64) void k_beff_w(
    const float* __restrict__ proj_w,
    const float* __restrict__ conv_b,
    const float* __restrict__ proj_b,
    const float* __restrict__ alpha,
    float* __restrict__ beff)
{
  int d = blockIdx.x;
  int lane = threadIdx.x;
  const float* pr = proj_w + d * F_;
  float acc = 0.f;
  #pragma unroll
  for (int p = 0; p < 9; ++p) {
    float v = 0.f;
    if (lane < E_) v = pr[lane * 9 + p] * conv_b[lane];
    #pragma unroll
    for (int off = 32; off > 0; off >>= 1) v += __shfl_xor(v, off, 64);
    acc += (1.f - sigmoidf_(alpha[p])) * v;
  }
  if (lane == 0) beff[d] = proj_b[d] + acc;
}

__global__ __launch_bounds__(256) void k_init(
    const float* __restrict__ beff, float* __restrict__ out)
{
  int idx = blockIdx.x * 256 + threadIdx.x;
  ((float4*)out)[idx] = ((const float4*)beff)[idx & 127];
}

__global__ __launch_bounds__(256) void k_accq(
    const int* __restrict__ x,
    const float* __restrict__ emb,
    const unsigned short* __restrict__ Wt,
    float* __restrict__ out, int q)
{
  const int tid = threadIdx.x;
  const int d = blockIdx.y * 256 + tid;
  const int row0 = blockIdx.x * 512;
  const unsigned short* wq = Wt + (size_t)(q * E_) * DIM_ + d;

  for (int rb = 0; rb < 512; rb += 8) {
    int tv[8]; float a[8];
    #pragma unroll
    for (int j = 0; j < 8; ++j) {
      tv[j] = x[(size_t)(row0 + rb + j) * 9 + q];
      a[j] = 0.f;
    }
    for (int c = 0; c < E_; ++c) {
      float w = bf2f_(wq[(size_t)c * DIM_]);
      #pragma unroll
      for (int j = 0; j < 8; ++j)
        a[j] += emb[tv[j] * E_ + c] * w;
    }
    #pragma unroll
    for (int j = 0; j < 8; ++j) {
      size_t o = (size_t)(row0 + rb + j) * DIM_ + d;
      out[o] += a[j];
    }
  }
}

__global__ __launch_bounds__(256) void k_ln(
    const float* __restrict__ gamma, const float* __restrict__ beta,
    float* __restrict__ out)
{
  int gid = blockIdx.x * 256 + threadIdx.x;
  int row = gid >> 6;
  int lane = threadIdx.x & 63;
  float* op = out + (size_t)row * DIM_ + lane * 8;
  float4 A0 = *(float4*)op, A1 = *(float4*)(op + 4);
  float a[8] = {A0.x, A0.y, A0.z, A0.w, A1.x, A1.y, A1.z, A1.w};
  float mu, rstd;
  ln_reduce_(a, mu, rstd);
  const float4* g4  = (const float4*)gamma;
  const float4* be4 = (const float4*)beta;
  float4 G0 = g4[2 * lane], G1 = g4[2 * lane + 1];
  float4 P0 = be4[2 * lane], P1 = be4[2 * lane + 1];
  float4 o0, o1;
  o0.x = (a[0] - mu) * rstd * G0.x + P0.x;
  o0.y = (a[1] - mu) * rstd * G0.y + P0.y;
  o0.z = (a[2] - mu) * rstd * G0.z + P0.z;
  o0.w = (a[3] - mu) * rstd * G0.w + P0.w;
  o1.x = (a[4] - mu) * rstd * G1.x + P1.x;
  o1.y = (a[5] - mu) * rstd * G1.y + P1.y;
  o1.z = (a[6] - mu) * rstd * G1.z + P1.z;
  o1.w = (a[7] - mu) * rstd * G1.w + P1.w;
  *(float4*)op = o0;
  *(float4*)(op + 4) = o1;
}

extern "C" void kernel_launch(void* const* d_in, const int* in_sizes, int n_in,
                              void* d_out, int out_size, void* d_ws, size_t ws_size,
                              hipStream_t stream) {
  const int*   x      = (const int*)  d_in[0];
  const float* emb    = (const float*)d_in[1];
  const float* alpha  = (const float*)d_in[2];
  const float* conv_w = (const float*)d_in[3];
  const float* conv_b = (const float*)d_in[4];
  const float* proj_w = (const float*)d_in[5];
  const float* proj_b = (const float*)d_in[6];
  const float* gamma  = (const float*)d_in[7];
  const float* beta   = (const float*)d_in[8];
  float* out = (float*)d_out;

  float* beff = (float*)d_ws;
  char* wsbase = (char*)d_ws;

  const size_t OFF_WT  = 2048;
  const size_t OFF_PW2 = OFF_WT  + (size_t)9 * E_ * DIM_ * 4;    // 1,034,240
  const size_t OFF_CT  = OFF_PW2 + (size_t)9 * DIM_ * E_ * 4;    // 2,066,432
  const size_t OFF_T   = OFF_CT  + (size_t)E_ * 9 * E_ * 4;      // 2,179,328
  const size_t needMain = OFF_T + (size_t)9 * V_ * DIM_ * 2;     // 4,538,624

  if (ws_size >= needMain) {
    float* Wt  = (float*)(wsbase + OFF_WT);
    float* PW2 = (float*)(wsbase + OFF_PW2);
    float* Ct  = (float*)(wsbase + OFF_CT);
    unsigned short* T = (unsigned short*)(wsbase + OFF_T);
    hipLaunchKernelGGL(k_pre, dim3(1247), dim3(256), 0, stream,
                       proj_w, conv_w, conv_b, proj_b, alpha, PW2, Ct, beff);
    hipLaunchKernelGGL(k_weff2, dim3((DIM_ * F_) / 256), dim3(256), 0, stream,
                       proj_w, PW2, Ct, alpha, Wt);
    hipLaunchKernelGGL(k_tab8b, dim3(9 * 32), dim3(256), 0, stream,
                       emb, Wt, beff, T);
    hipLaunchKernelGGL(k_main4c, dim3(NROWS / 16), dim3(256), 0, stream,
                       x, T, gamma, beta, out);
  } else {
    unsigned short* Wt = (unsigned short*)(wsbase + 2048);
    hipLaunchKernelGGL(k_beff_w, dim3(DIM_), dim3(64), 0, stream,
                       proj_w, conv_b, proj_b, alpha, beff);
    hipLaunchKernelGGL(k_weff_bf, dim3((DIM_ * F_) / 256), dim3(256), 0, stream,
                       proj_w, conv_w, alpha, Wt);
    hipLaunchKernelGGL(k_init, dim3((NROWS * DIM_ / 4) / 256), dim3(256), 0, stream,
                       beff, out);
    for (int q = 0; q < 9; ++q)
      hipLaunchKernelGGL(k_accq, dim3(128, 2), dim3(256), 0, stream,
                         x, emb, Wt, out, q);
    hipLaunchKernelGGL(k_ln, dim3(NROWS / 4), dim3(256), 0, stream,
                       gamma, beta, out);
  }
}

// Round 14
// 119.029 us; speedup vs baseline: 1.2945x; 1.2945x over previous
//
#include <hip/hip_runtime.h>

#define E_ 56
#define DIM_ 512
#define V_ 256
#define F_ 504       // E_*9
#define NROWS 65536  // B*L

typedef float  vf4 __attribute__((ext_vector_type(4)));

__device__ __forceinline__ float sigmoidf_(float v) { return 1.0f / (1.0f + expf(-v)); }
__device__ __forceinline__ float bf_lo_(unsigned int u) {
  return __uint_as_float(u << 16);
}
__device__ __forceinline__ float bf_hi_(unsigned int u) {
  return __uint_as_float(u & 0xFFFF0000u);
}
__device__ __forceinline__ float bf2f_(unsigned short u) {
  return __uint_as_float(((unsigned int)u) << 16);
}
__device__ __forceinline__ unsigned short f2bf_(float f) {  // round-nearest-even
  unsigned int b = __float_as_uint(f);
  b += 0x7FFFu + ((b >> 16) & 1u);
  return (unsigned short)(b >> 16);
}

// ---- fused: transposes + beff ---------------------------------------------
__global__ __launch_bounds__(256) void k_pre(
    const float* __restrict__ proj_w,   // [512][504]
    const float* __restrict__ conv_w,   // [56][504]
    const float* __restrict__ conv_b,   // [56]
    const float* __restrict__ proj_b,   // [512]
    const float* __restrict__ alpha,    // [9]
    float* __restrict__ PW2,            // [9][512][56]
    float* __restrict__ Ct,             // [56][9][56]
    float* __restrict__ beff)           // [512]
{
  int b = blockIdx.x;
  if (b < 1008) {
    int idx = b * 256 + threadIdx.x;
    int p = idx / (DIM_ * E_);
    int r = idx - p * (DIM_ * E_);
    int d = r / E_;
    int e = r - d * E_;
    PW2[idx] = proj_w[d * F_ + e * 9 + p];
  } else if (b < 1119) {
    int j = (b - 1008) * 256 + threadIdx.x;
    if (j < E_ * 9 * E_) {              // 28224
      int c = j / (9 * E_);
      int r = j - c * (9 * E_);
      int k = r / E_;
      int e = r - k * E_;
      Ct[j] = conv_w[e * F_ + c * 9 + k];
    }
  } else {
    int d = (b - 1119) * 4 + (threadIdx.x >> 6);
    int lane = threadIdx.x & 63;
    const float* pr = proj_w + d * F_;
    float acc = 0.f;
    #pragma unroll
    for (int p = 0; p < 9; ++p) {
      float v = 0.f;
      if (lane < E_) v = pr[lane * 9 + p] * conv_b[lane];
      #pragma unroll
      for (int off = 32; off > 0; off >>= 1) v += __shfl_xor(v, off, 64);
      acc += (1.f - sigmoidf_(alpha[p])) * v;
    }
    if (lane == 0) beff[d] = proj_b[d] + acc;
  }
}

// ---- Weff fold (R6-proven; 1008 blocks keeps the GPU saturated) -----------
__global__ __launch_bounds__(256) void k_weff2(
    const float* __restrict__ proj_w,   // [512][504]
    const float* __restrict__ PW2,      // [9][512][56]
    const float* __restrict__ Ct,       // [56][9][56]
    const float* __restrict__ alpha,    // [9]
    float* __restrict__ Wt)             // [9][56][512] f32
{
  int idx = blockIdx.x * 256 + threadIdx.x;   // 512*504 threads
  int d = idx / F_;
  int f = idx - d * F_;
  int c = f / 9;
  int q = f - c * 9;
  int qi = q / 3, qj = q - qi * 3;
  float acc = sigmoidf_(alpha[q]) * proj_w[d * F_ + c * 9 + q];
  #pragma unroll
  for (int p = 0; p < 9; ++p) {
    int pi = p / 3, pj = p - pi * 3;
    int ki = qi - pi + 1, kj = qj - pj + 1;
    if (ki < 0 || ki > 2 || kj < 0 || kj > 2) continue;
    const vf4* A = (const vf4*)(PW2 + (p * DIM_ + d) * E_);
    const vf4* B = (const vf4*)(Ct + (c * 9 + (ki * 3 + kj)) * E_);
    vf4 sv = {0.f, 0.f, 0.f, 0.f};
    #pragma unroll
    for (int e4 = 0; e4 < E_ / 4; ++e4)
      sv += A[e4] * B[e4];
    float s = sv.x + sv.y + sv.z + sv.w;
    acc += (1.f - sigmoidf_(alpha[p])) * s;
  }
  Wt[(size_t)(q * E_ + c) * DIM_ + d] = acc;
}

// T[q][t][d] = beff[d]/9 + sum_c emb[t][c] * Wt[q][c][d]   (bias folded)
__global__ __launch_bounds__(256) void k_tab8b(
    const float* __restrict__ emb,      // [256][56]
    const float* __restrict__ Wt,       // [9][56][512] f32
    const float* __restrict__ beff,     // [512]
    unsigned short* __restrict__ T)     // [9][256][512] bf16
{
  int q  = blockIdx.x >> 5;
  int t0 = (blockIdx.x & 31) * 8;
  int d0 = 2 * threadIdx.x;
  const float inv9 = 1.0f / 9.0f;
  float2 bv = *(const float2*)(beff + d0);
  float b0 = bv.x * inv9, b1 = bv.y * inv9;
  float a0[8], a1[8];
  #pragma unroll
  for (int j = 0; j < 8; ++j) { a0[j] = b0; a1[j] = b1; }
  for (int c = 0; c < E_; ++c) {
    float2 w = *(const float2*)(Wt + (size_t)(q * E_ + c) * DIM_ + d0);
    #pragma unroll
    for (int j = 0; j < 8; ++j) {
      float ev = emb[(t0 + j) * E_ + c];   // uniform -> scalar load
      a0[j] += ev * w.x;
      a1[j] += ev * w.y;
    }
  }
  #pragma unroll
  for (int j = 0; j < 8; ++j) {
    size_t o = (size_t)((q << 8) + t0 + j) * DIM_ + d0;
    unsigned int u = (unsigned int)f2bf_(a0[j]) | ((unsigned int)f2bf_(a1[j]) << 16);
    *(unsigned int*)(T + o) = u;
  }
}

// Shared LayerNorm tail helper ----------------------------------------------
__device__ __forceinline__ void ln_reduce_(const float a[8], float& mu, float& rstd) {
  float s = 0.f, ss = 0.f;
  #pragma unroll
  for (int j = 0; j < 8; ++j) { s += a[j]; ss += a[j] * a[j]; }
  #pragma unroll
  for (int off = 32; off > 0; off >>= 1) {
    s  += __shfl_xor(s, off, 64);
    ss += __shfl_xor(ss, off, 64);
  }
  mu = s * (1.0f / 512.0f);
  float var = ss * (1.0f / 512.0f) - mu * mu;
  rstd = rsqrtf(var + 1e-5f);
}

// 4 rows per wave, 2-deep gather pipeline; gamma/beta hoisted per wave.
// T gathers via AGENT-scope relaxed loads: bypass the (non-coherent, 32KB,
// 0%-hit) L1 but still allocate in L2 — unlike R13's nt loads which demoted
// lines in L2 too (FETCH_SIZE blew up to 40MB -> regression).
__global__ __launch_bounds__(256) void k_main4d(
    const int*            __restrict__ x,     // [65536][9]
    const unsigned short* __restrict__ T,     // [9][256][512] bf16 (biased)
    const float* __restrict__ gamma,
    const float* __restrict__ beta,
    float* __restrict__ out)                  // [65536][512]
{
  int lane = threadIdx.x & 63;
  int wid  = __builtin_amdgcn_readfirstlane(threadIdx.x >> 6);
  int row0 = blockIdx.x * 16 + wid * 4;       // grid = NROWS/16
  const int* __restrict__ xr = x + row0 * 9;  // uniform -> s_load

  const float4* g4  = (const float4*)gamma;
  const float4* be4 = (const float4*)beta;
  float4 G0 = g4[2 * lane],  G1 = g4[2 * lane + 1];
  float4 P0 = be4[2 * lane], P1 = be4[2 * lane + 1];

  unsigned long long curA[9], curB[9], nxtA[9], nxtB[9];
  #pragma unroll
  for (int q = 0; q < 9; ++q) {
    const unsigned long long* Tq = (const unsigned long long*)
        (T + (size_t)((q << 8) + xr[q]) * DIM_) + 2 * lane;
    curA[q] = __hip_atomic_load(Tq,     __ATOMIC_RELAXED, __HIP_MEMORY_SCOPE_AGENT);
    curB[q] = __hip_atomic_load(Tq + 1, __ATOMIC_RELAXED, __HIP_MEMORY_SCOPE_AGENT);
  }

  #pragma unroll
  for (int r = 0; r < 4; ++r) {
    if (r < 3) {
      #pragma unroll
      for (int q = 0; q < 9; ++q) {
        const unsigned long long* Tq = (const unsigned long long*)
            (T + (size_t)((q << 8) + xr[(r + 1) * 9 + q]) * DIM_) + 2 * lane;
        nxtA[q] = __hip_atomic_load(Tq,     __ATOMIC_RELAXED, __HIP_MEMORY_SCOPE_AGENT);
        nxtB[q] = __hip_atomic_load(Tq + 1, __ATOMIC_RELAXED, __HIP_MEMORY_SCOPE_AGENT);
      }
    }

    float a[8] = {0.f, 0.f, 0.f, 0.f, 0.f, 0.f, 0.f, 0.f};
    #pragma unroll
    for (int q = 0; q < 9; ++q) {
      unsigned int u0 = (unsigned int)curA[q];
      unsigned int u1 = (unsigned int)(curA[q] >> 32);
      unsigned int u2 = (unsigned int)curB[q];
      unsigned int u3 = (unsigned int)(curB[q] >> 32);
      a[0] += bf_lo_(u0); a[1] += bf_hi_(u0);
      a[2] += bf_lo_(u1); a[3] += bf_hi_(u1);
      a[4] += bf_lo_(u2); a[5] += bf_hi_(u2);
      a[6] += bf_lo_(u3); a[7] += bf_hi_(u3);
    }

    float mu, rstd;
    ln_reduce_(a, mu, rstd);

    vf4 o0, o1;
    o0.x = (a[0] - mu) * rstd * G0.x + P0.x;
    o0.y = (a[1] - mu) * rstd * G0.y + P0.y;
    o0.z = (a[2] - mu) * rstd * G0.z + P0.z;
    o0.w = (a[3] - mu) * rstd * G0.w + P0.w;
    o1.x = (a[4] - mu) * rstd * G1.x + P1.x;
    o1.y = (a[5] - mu) * rstd * G1.y + P1.y;
    o1.z = (a[6] - mu) * rstd * G1.z + P1.z;
    o1.w = (a[7] - mu) * rstd * G1.w + P1.w;

    vf4* o4 = (vf4*)(out + (size_t)(row0 + r) * DIM_ + lane * 8);
    __builtin_nontemporal_store(o0, o4);
    __builtin_nontemporal_store(o1, o4 + 1);

    if (r < 3) {
      #pragma unroll
      for (int q = 0; q < 9; ++q) {
        curA[q] = nxtA[q];
        curB[q] = nxtB[q];
      }
    }
  }
}

// ----------------- tiny-ws fallback ----------------------------------------
__global__ __launch_bounds__(256) void k_weff_bf(
    const float* __restrict__ proj_w,
    const float* __restrict__ conv_w,
    const float* __restrict__ alpha,
    unsigned short* __restrict__ Wt)
{
  int idx = blockIdx.x * 256 + threadIdx.x;
  int d = idx / F_;
  int f = idx - d * F_;
  int c = f / 9;
  int q = f - c * 9;
  int qi = q / 3, qj = q - qi * 3;
  const float* pr = proj_w + d * F_;
  float acc = sigmoidf_(alpha[q]) * pr[c * 9 + q];
  for (int pi = 0; pi < 3; ++pi) {
    for (int pj = 0; pj < 3; ++pj) {
      int ki = qi - pi + 1, kj = qj - pj + 1;
      if (ki < 0 || ki > 2 || kj < 0 || kj > 2) continue;
      int p = pi * 3 + pj;
      const float* cwp = conv_w + c * 9 + (ki * 3 + kj);
      const float* prp = pr + p;
      float s = 0.f;
      #pragma unroll 8
      for (int e = 0; e < E_; ++e)
        s += prp[e * 9] * cwp[e * F_];
      acc += (1.f - sigmoidf_(alpha[p])) * s;
    }
  }
  Wt[(size_t)(q * E_ + c) * DIM_ + d] = f2bf_(acc);
}

__global__ __launch_bounds__(64) void k_beff_w(
    const float* __restrict__ proj_w,
    const float* __restrict__ conv_b,
    const float* __restrict__ proj_b,
    const float* __restrict__ alpha,
    float* __restrict__ beff)
{
  int d = blockIdx.x;
  int lane = threadIdx.x;
  const float* pr = proj_w + d * F_;
  float acc = 0.f;
  #pragma unroll
  for (int p = 0; p < 9; ++p) {
    float v = 0.f;
    if (lane < E_) v = pr[lane * 9 + p] * conv_b[lane];
    #pragma unroll
    for (int off = 32; off > 0; off >>= 1) v += __shfl_xor(v, off, 64);
    acc += (1.f - sigmoidf_(alpha[p])) * v;
  }
  if (lane == 0) beff[d] = proj_b[d] + acc;
}

__global__ __launch_bounds__(256) void k_init(
    const float* __restrict__ beff, float* __restrict__ out)
{
  int idx = blockIdx.x * 256 + threadIdx.x;
  ((float4*)out)[idx] = ((const float4*)beff)[idx & 127];
}

__global__ __launch_bounds__(256) void k_accq(
    const int* __restrict__ x,
    const float* __restrict__ emb,
    const unsigned short* __restrict__ Wt,
    float* __restrict__ out, int q)
{
  const int tid = threadIdx.x;
  const int d = blockIdx.y * 256 + tid;
  const int row0 = blockIdx.x * 512;
  const unsigned short* wq = Wt + (size_t)(q * E_) * DIM_ + d;

  for (int rb = 0; rb < 512; rb += 8) {
    int tv[8]; float a[8];
    #pragma unroll
    for (int j = 0; j < 8; ++j) {
      tv[j] = x[(size_t)(row0 + rb + j) * 9 + q];
      a[j] = 0.f;
    }
    for (int c = 0; c < E_; ++c) {
      float w = bf2f_(wq[(size_t)c * DIM_]);
      #pragma unroll
      for (int j = 0; j < 8; ++j)
        a[j] += emb[tv[j] * E_ + c] * w;
    }
    #pragma unroll
    for (int j = 0; j < 8; ++j) {
      size_t o = (size_t)(row0 + rb + j) * DIM_ + d;
      out[o] += a[j];
    }
  }
}

__global__ __launch_bounds__(256) void k_ln(
    const float* __restrict__ gamma, const float* __restrict__ beta,
    float* __restrict__ out)
{
  int gid = blockIdx.x * 256 + threadIdx.x;
  int row = gid >> 6;
  int lane = threadIdx.x & 63;
  float* op = out + (size_t)row * DIM_ + lane * 8;
  float4 A0 = *(float4*)op, A1 = *(float4*)(op + 4);
  float a[8] = {A0.x, A0.y, A0.z, A0.w, A1.x, A1.y, A1.z, A1.w};
  float mu, rstd;
  ln_reduce_(a, mu, rstd);
  const float4* g4  = (const float4*)gamma;
  const float4* be4 = (const float4*)beta;
  float4 G0 = g4[2 * lane], G1 = g4[2 * lane + 1];
  float4 P0 = be4[2 * lane], P1 = be4[2 * lane + 1];
  float4 o0, o1;
  o0.x = (a[0] - mu) * rstd * G0.x + P0.x;
  o0.y = (a[1] - mu) * rstd * G0.y + P0.y;
  o0.z = (a[2] - mu) * rstd * G0.z + P0.z;
  o0.w = (a[3] - mu) * rstd * G0.w + P0.w;
  o1.x = (a[4] - mu) * rstd * G1.x + P1.x;
  o1.y = (a[5] - mu) * rstd * G1.y + P1.y;
  o1.z = (a[6] - mu) * rstd * G1.z + P1.z;
  o1.w = (a[7] - mu) * rstd * G1.w + P1.w;
  *(float4*)op = o0;
  *(float4*)(op + 4) = o1;
}

extern "C" void kernel_launch(void* const* d_in, const int* in_sizes, int n_in,
                              void* d_out, int out_size, void* d_ws, size_t ws_size,
                              hipStream_t stream) {
  const int*   x      = (const int*)  d_in[0];
  const float* emb    = (const float*)d_in[1];
  const float* alpha  = (const float*)d_in[2];
  const float* conv_w = (const float*)d_in[3];
  const float* conv_b = (const float*)d_in[4];
  const float* proj_w = (const float*)d_in[5];
  const float* proj_b = (const float*)d_in[6];
  const float* gamma  = (const float*)d_in[7];
  const float* beta   = (const float*)d_in[8];
  float* out = (float*)d_out;

  float* beff = (float*)d_ws;
  char* wsbase = (char*)d_ws;

  const size_t OFF_WT  = 2048;
  const size_t OFF_PW2 = OFF_WT  + (size_t)9 * E_ * DIM_ * 4;    // 1,034,240
  const size_t OFF_CT  = OFF_PW2 + (size_t)9 * DIM_ * E_ * 4;    // 2,066,432
  const size_t OFF_T   = OFF_CT  + (size_t)E_ * 9 * E_ * 4;      // 2,179,328
  const size_t needMain = OFF_T + (size_t)9 * V_ * DIM_ * 2;     // 4,538,624

  if (ws_size >= needMain) {
    float* Wt  = (float*)(wsbase + OFF_WT);
    float* PW2 = (float*)(wsbase + OFF_PW2);
    float* Ct  = (float*)(wsbase + OFF_CT);
    unsigned short* T = (unsigned short*)(wsbase + OFF_T);
    hipLaunchKernelGGL(k_pre, dim3(1247), dim3(256), 0, stream,
                       proj_w, conv_w, conv_b, proj_b, alpha, PW2, Ct, beff);
    hipLaunchKernelGGL(k_weff2, dim3((DIM_ * F_) / 256), dim3(256), 0, stream,
                       proj_w, PW2, Ct, alpha, Wt);
    hipLaunchKernelGGL(k_tab8b, dim3(9 * 32), dim3(256), 0, stream,
                       emb, Wt, beff, T);
    hipLaunchKernelGGL(k_main4d, dim3(NROWS / 16), dim3(256), 0, stream,
                       x, T, gamma, beta, out);
  } else {
    unsigned short* Wt = (unsigned short*)(wsbase + 2048);
    hipLaunchKernelGGL(k_beff_w, dim3(DIM_), dim3(64), 0, stream,
                       proj_w, conv_b, proj_b, alpha, beff);
    hipLaunchKernelGGL(k_weff_bf, dim3((DIM_ * F_) / 256), dim3(256), 0, stream,
                       proj_w, conv_w, alpha, Wt);
    hipLaunchKernelGGL(k_init, dim3((NROWS * DIM_ / 4) / 256), dim3(256), 0, stream,
                       beff, out);
    for (int q = 0; q < 9; ++q)
      hipLaunchKernelGGL(k_accq, dim3(128, 2), dim3(256), 0, stream,
                         x, emb, Wt, out, q);
    hipLaunchKernelGGL(k_ln, dim3(NROWS / 4), dim3(256), 0, stream,
                       gamma, beta, out);
  }
}

// Round 15
// 100.750 us; speedup vs baseline: 1.5294x; 1.1814x over previous
//
#include <hip/hip_runtime.h>

#define E_ 56
#define DIM_ 512
#define V_ 256
#define F_ 504       // E_*9
#define NROWS 65536  // B*L

typedef float  vf4 __attribute__((ext_vector_type(4)));

__device__ __forceinline__ float sigmoidf_(float v) { return 1.0f / (1.0f + expf(-v)); }
__device__ __forceinline__ float bf_lo_(unsigned int u) {
  return __uint_as_float(u << 16);
}
__device__ __forceinline__ float bf_hi_(unsigned int u) {
  return __uint_as_float(u & 0xFFFF0000u);
}
__device__ __forceinline__ float bf2f_(unsigned short u) {
  return __uint_as_float(((unsigned int)u) << 16);
}
__device__ __forceinline__ unsigned short f2bf_(float f) {  // round-nearest-even
  unsigned int b = __float_as_uint(f);
  b += 0x7FFFu + ((b >> 16) & 1u);
  return (unsigned short)(b >> 16);
}

// ---- fused: transposes + beff ---------------------------------------------
__global__ __launch_bounds__(256) void k_pre(
    const float* __restrict__ proj_w,   // [512][504]
    const float* __restrict__ conv_w,   // [56][504]
    const float* __restrict__ conv_b,   // [56]
    const float* __restrict__ proj_b,   // [512]
    const float* __restrict__ alpha,    // [9]
    float* __restrict__ PW2,            // [9][512][56]
    float* __restrict__ Ct,             // [56][9][56]
    float* __restrict__ beff)           // [512]
{
  int b = blockIdx.x;
  if (b < 1008) {
    int idx = b * 256 + threadIdx.x;
    int p = idx / (DIM_ * E_);
    int r = idx - p * (DIM_ * E_);
    int d = r / E_;
    int e = r - d * E_;
    PW2[idx] = proj_w[d * F_ + e * 9 + p];
  } else if (b < 1119) {
    int j = (b - 1008) * 256 + threadIdx.x;
    if (j < E_ * 9 * E_) {              // 28224
      int c = j / (9 * E_);
      int r = j - c * (9 * E_);
      int k = r / E_;
      int e = r - k * E_;
      Ct[j] = conv_w[e * F_ + c * 9 + k];
    }
  } else {
    int d = (b - 1119) * 4 + (threadIdx.x >> 6);
    int lane = threadIdx.x & 63;
    const float* pr = proj_w + d * F_;
    float acc = 0.f;
    #pragma unroll
    for (int p = 0; p < 9; ++p) {
      float v = 0.f;
      if (lane < E_) v = pr[lane * 9 + p] * conv_b[lane];
      #pragma unroll
      for (int off = 32; off > 0; off >>= 1) v += __shfl_xor(v, off, 64);
      acc += (1.f - sigmoidf_(alpha[p])) * v;
    }
    if (lane == 0) beff[d] = proj_b[d] + acc;
  }
}

// ---- Weff fold (R6-proven; 1008 blocks keeps the GPU saturated) -----------
__global__ __launch_bounds__(256) void k_weff2(
    const float* __restrict__ proj_w,   // [512][504]
    const float* __restrict__ PW2,      // [9][512][56]
    const float* __restrict__ Ct,       // [56][9][56]
    const float* __restrict__ alpha,    // [9]
    float* __restrict__ Wt)             // [9][56][512] f32
{
  int idx = blockIdx.x * 256 + threadIdx.x;   // 512*504 threads
  int d = idx / F_;
  int f = idx - d * F_;
  int c = f / 9;
  int q = f - c * 9;
  int qi = q / 3, qj = q - qi * 3;
  float acc = sigmoidf_(alpha[q]) * proj_w[d * F_ + c * 9 + q];
  #pragma unroll
  for (int p = 0; p < 9; ++p) {
    int pi = p / 3, pj = p - pi * 3;
    int ki = qi - pi + 1, kj = qj - pj + 1;
    if (ki < 0 || ki > 2 || kj < 0 || kj > 2) continue;
    const vf4* A = (const vf4*)(PW2 + (p * DIM_ + d) * E_);
    const vf4* B = (const vf4*)(Ct + (c * 9 + (ki * 3 + kj)) * E_);
    vf4 sv = {0.f, 0.f, 0.f, 0.f};
    #pragma unroll
    for (int e4 = 0; e4 < E_ / 4; ++e4)
      sv += A[e4] * B[e4];
    float s = sv.x + sv.y + sv.z + sv.w;
    acc += (1.f - sigmoidf_(alpha[p])) * s;
  }
  Wt[(size_t)(q * E_ + c) * DIM_ + d] = acc;
}

// T[q][t][d] = beff[d]/9 + sum_c emb[t][c] * Wt[q][c][d]   (bias folded)
__global__ __launch_bounds__(256) void k_tab8b(
    const float* __restrict__ emb,      // [256][56]
    const float* __restrict__ Wt,       // [9][56][512] f32
    const float* __restrict__ beff,     // [512]
    unsigned short* __restrict__ T)     // [9][256][512] bf16
{
  int q  = blockIdx.x >> 5;
  int t0 = (blockIdx.x & 31) * 8;
  int d0 = 2 * threadIdx.x;
  const float inv9 = 1.0f / 9.0f;
  float2 bv = *(const float2*)(beff + d0);
  float b0 = bv.x * inv9, b1 = bv.y * inv9;
  float a0[8], a1[8];
  #pragma unroll
  for (int j = 0; j < 8; ++j) { a0[j] = b0; a1[j] = b1; }
  for (int c = 0; c < E_; ++c) {
    float2 w = *(const float2*)(Wt + (size_t)(q * E_ + c) * DIM_ + d0);
    #pragma unroll
    for (int j = 0; j < 8; ++j) {
      float ev = emb[(t0 + j) * E_ + c];   // uniform -> scalar load
      a0[j] += ev * w.x;
      a1[j] += ev * w.y;
    }
  }
  #pragma unroll
  for (int j = 0; j < 8; ++j) {
    size_t o = (size_t)((q << 8) + t0 + j) * DIM_ + d0;
    unsigned int u = (unsigned int)f2bf_(a0[j]) | ((unsigned int)f2bf_(a1[j]) << 16);
    *(unsigned int*)(T + o) = u;
  }
}

// Shared LayerNorm tail helper ----------------------------------------------
__device__ __forceinline__ void ln_reduce_(const float a[8], float& mu, float& rstd) {
  float s = 0.f, ss = 0.f;
  #pragma unroll
  for (int j = 0; j < 8; ++j) { s += a[j]; ss += a[j] * a[j]; }
  #pragma unroll
  for (int off = 32; off > 0; off >>= 1) {
    s  += __shfl_xor(s, off, 64);
    ss += __shfl_xor(ss, off, 64);
  }
  mu = s * (1.0f / 512.0f);
  float var = ss * (1.0f / 512.0f) - mu * mu;
  rstd = rsqrtf(var + 1e-5f);
}

// 4 rows per wave; gamma/beta hoisted per wave. Plain vector gathers (L1
// path): NT loads (R13) killed L2 residency, agent atomics (R14) split the
// loads — both regressed. The gather rate is MSHR*latency-bound; this is
// the best-measured form (R12: 101us).
__global__ __launch_bounds__(256) void k_main4b(
    const int*            __restrict__ x,     // [65536][9]
    const unsigned short* __restrict__ T,     // [9][256][512] bf16 (biased)
    const float* __restrict__ gamma,
    const float* __restrict__ beta,
    float* __restrict__ out)                  // [65536][512]
{
  int lane = threadIdx.x & 63;
  int wid  = __builtin_amdgcn_readfirstlane(threadIdx.x >> 6);
  int row0 = blockIdx.x * 16 + wid * 4;       // grid = NROWS/16
  const int* __restrict__ xr = x + row0 * 9;  // uniform -> s_load

  const float4* g4  = (const float4*)gamma;
  const float4* be4 = (const float4*)beta;
  float4 G0 = g4[2 * lane],  G1 = g4[2 * lane + 1];
  float4 P0 = be4[2 * lane], P1 = be4[2 * lane + 1];

  uint4 cur[9], nxt[9];
  #pragma unroll
  for (int q = 0; q < 9; ++q)
    cur[q] = *((const uint4*)(T + (size_t)((q << 8) + xr[q]) * DIM_) + lane);

  #pragma unroll
  for (int r = 0; r < 4; ++r) {
    if (r < 3) {
      #pragma unroll
      for (int q = 0; q < 9; ++q)
        nxt[q] = *((const uint4*)(T + (size_t)((q << 8) + xr[(r + 1) * 9 + q]) * DIM_) + lane);
    }

    float a[8] = {0.f, 0.f, 0.f, 0.f, 0.f, 0.f, 0.f, 0.f};
    #pragma unroll
    for (int q = 0; q < 9; ++q) {
      a[0] += bf_lo_(cur[q].x); a[1] += bf_hi_(cur[q].x);
      a[2] += bf_lo_(cur[q].y); a[3] += bf_hi_(cur[q].y);
      a[4] += bf_lo_(cur[q].z); a[5] += bf_hi_(cur[q].z);
      a[6] += bf_lo_(cur[q].w); a[7] += bf_hi_(cur[q].w);
    }

    float mu, rstd;
    ln_reduce_(a, mu, rstd);

    vf4 o0, o1;
    o0.x = (a[0] - mu) * rstd * G0.x + P0.x;
    o0.y = (a[1] - mu) * rstd * G0.y + P0.y;
    o0.z = (a[2] - mu) * rstd * G0.z + P0.z;
    o0.w = (a[3] - mu) * rstd * G0.w + P0.w;
    o1.x = (a[4] - mu) * rstd * G1.x + P1.x;
    o1.y = (a[5] - mu) * rstd * G1.y + P1.y;
    o1.z = (a[6] - mu) * rstd * G1.z + P1.z;
    o1.w = (a[7] - mu) * rstd * G1.w + P1.w;

    vf4* o4 = (vf4*)(out + (size_t)(row0 + r) * DIM_ + lane * 8);
    __builtin_nontemporal_store(o0, o4);
    __builtin_nontemporal_store(o1, o4 + 1);

    if (r < 3) {
      #pragma unroll
      for (int q = 0; q < 9; ++q) cur[q] = nxt[q];
    }
  }
}

// ----------------- tiny-ws fallback ----------------------------------------
__global__ __launch_bounds__(256) void k_weff_bf(
    const float* __restrict__ proj_w,
    const float* __restrict__ conv_w,
    const float* __restrict__ alpha,
    unsigned short* __restrict__ Wt)
{
  int idx = blockIdx.x * 256 + threadIdx.x;
  int d = idx / F_;
  int f = idx - d * F_;
  int c = f / 9;
  int q = f - c * 9;
  int qi = q / 3, qj = q - qi * 3;
  const float* pr = proj_w + d * F_;
  float acc = sigmoidf_(alpha[q]) * pr[c * 9 + q];
  for (int pi = 0; pi < 3; ++pi) {
    for (int pj = 0; pj < 3; ++pj) {
      int ki = qi - pi + 1, kj = qj - pj + 1;
      if (ki < 0 || ki > 2 || kj < 0 || kj > 2) continue;
      int p = pi * 3 + pj;
      const float* cwp = conv_w + c * 9 + (ki * 3 + kj);
      const float* prp = pr + p;
      float s = 0.f;
      #pragma unroll 8
      for (int e = 0; e < E_; ++e)
        s += prp[e * 9] * cwp[e * F_];
      acc += (1.f - sigmoidf_(alpha[p])) * s;
    }
  }
  Wt[(size_t)(q * E_ + c) * DIM_ + d] = f2bf_(acc);
}

__global__ __launch_bounds__(64) void k_beff_w(
    const float* __restrict__ proj_w,
    const float* __restrict__ conv_b,
    const float* __restrict__ proj_b,
    const float* __restrict__ alpha,
    float* __restrict__ beff)
{
  int d = blockIdx.x;
  int lane = threadIdx.x;
  const float* pr = proj_w + d * F_;
  float acc = 0.f;
  #pragma unroll
  for (int p = 0; p < 9; ++p) {
    float v = 0.f;
    if (lane < E_) v = pr[lane * 9 + p] * conv_b[lane];
    #pragma unroll
    for (int off = 32; off > 0; off >>= 1) v += __shfl_xor(v, off, 64);
    acc += (1.f - sigmoidf_(alpha[p])) * v;
  }
  if (lane == 0) beff[d] = proj_b[d] + acc;
}

__global__ __launch_bounds__(256) void k_init(
    const float* __restrict__ beff, float* __restrict__ out)
{
  int idx = blockIdx.x * 256 + threadIdx.x;
  ((float4*)out)[idx] = ((const float4*)beff)[idx & 127];
}

__global__ __launch_bounds__(256) void k_accq(
    const int* __restrict__ x,
    const float* __restrict__ emb,
    const unsigned short* __restrict__ Wt,
    float* __restrict__ out, int q)
{
  const int tid = threadIdx.x;
  const int d = blockIdx.y * 256 + tid;
  const int row0 = blockIdx.x * 512;
  const unsigned short* wq = Wt + (size_t)(q * E_) * DIM_ + d;

  for (int rb = 0; rb < 512; rb += 8) {
    int tv[8]; float a[8];
    #pragma unroll
    for (int j = 0; j < 8; ++j) {
      tv[j] = x[(size_t)(row0 + rb + j) * 9 + q];
      a[j] = 0.f;
    }
    for (int c = 0; c < E_; ++c) {
      float w = bf2f_(wq[(size_t)c * DIM_]);
      #pragma unroll
      for (int j = 0; j < 8; ++j)
        a[j] += emb[tv[j] * E_ + c] * w;
    }
    #pragma unroll
    for (int j = 0; j < 8; ++j) {
      size_t o = (size_t)(row0 + rb + j) * DIM_ + d;
      out[o] += a[j];
    }
  }
}

__global__ __launch_bounds__(256) void k_ln(
    const float* __restrict__ gamma, const float* __restrict__ beta,
    float* __restrict__ out)
{
  int gid = blockIdx.x * 256 + threadIdx.x;
  int row = gid >> 6;
  int lane = threadIdx.x & 63;
  float* op = out + (size_t)row * DIM_ + lane * 8;
  float4 A0 = *(float4*)op, A1 = *(float4*)(op + 4);
  float a[8] = {A0.x, A0.y, A0.z, A0.w, A1.x, A1.y, A1.z, A1.w};
  float mu, rstd;
  ln_reduce_(a, mu, rstd);
  const float4* g4  = (const float4*)gamma;
  const float4* be4 = (const float4*)beta;
  float4 G0 = g4[2 * lane], G1 = g4[2 * lane + 1];
  float4 P0 = be4[2 * lane], P1 = be4[2 * lane + 1];
  float4 o0, o1;
  o0.x = (a[0] - mu) * rstd * G0.x + P0.x;
  o0.y = (a[1] - mu) * rstd * G0.y + P0.y;
  o0.z = (a[2] - mu) * rstd * G0.z + P0.z;
  o0.w = (a[3] - mu) * rstd * G0.w + P0.w;
  o1.x = (a[4] - mu) * rstd * G1.x + P1.x;
  o1.y = (a[5] - mu) * rstd * G1.y + P1.y;
  o1.z = (a[6] - mu) * rstd * G1.z + P1.z;
  o1.w = (a[7] - mu) * rstd * G1.w + P1.w;
  *(float4*)op = o0;
  *(float4*)(op + 4) = o1;
}

extern "C" void kernel_launch(void* const* d_in, const int* in_sizes, int n_in,
                              void* d_out, int out_size, void* d_ws, size_t ws_size,
                              hipStream_t stream) {
  const int*   x      = (const int*)  d_in[0];
  const float* emb    = (const float*)d_in[1];
  const float* alpha  = (const float*)d_in[2];
  const float* conv_w = (const float*)d_in[3];
  const float* conv_b = (const float*)d_in[4];
  const float* proj_w = (const float*)d_in[5];
  const float* proj_b = (const float*)d_in[6];
  const float* gamma  = (const float*)d_in[7];
  const float* beta   = (const float*)d_in[8];
  float* out = (float*)d_out;

  float* beff = (float*)d_ws;
  char* wsbase = (char*)d_ws;

  const size_t OFF_WT  = 2048;
  const size_t OFF_PW2 = OFF_WT  + (size_t)9 * E_ * DIM_ * 4;    // 1,034,240
  const size_t OFF_CT  = OFF_PW2 + (size_t)9 * DIM_ * E_ * 4;    // 2,066,432
  const size_t OFF_T   = OFF_CT  + (size_t)E_ * 9 * E_ * 4;      // 2,179,328
  const size_t needMain = OFF_T + (size_t)9 * V_ * DIM_ * 2;     // 4,538,624

  if (ws_size >= needMain) {
    float* Wt  = (float*)(wsbase + OFF_WT);
    float* PW2 = (float*)(wsbase + OFF_PW2);
    float* Ct  = (float*)(wsbase + OFF_CT);
    unsigned short* T = (unsigned short*)(wsbase + OFF_T);
    hipLaunchKernelGGL(k_pre, dim3(1247), dim3(256), 0, stream,
                       proj_w, conv_w, conv_b, proj_b, alpha, PW2, Ct, beff);
    hipLaunchKernelGGL(k_weff2, dim3((DIM_ * F_) / 256), dim3(256), 0, stream,
                       proj_w, PW2, Ct, alpha, Wt);
    hipLaunchKernelGGL(k_tab8b, dim3(9 * 32), dim3(256), 0, stream,
                       emb, Wt, beff, T);
    hipLaunchKernelGGL(k_main4b, dim3(NROWS / 16), dim3(256), 0, stream,
                       x, T, gamma, beta, out);
  } else {
    unsigned short* Wt = (unsigned short*)(wsbase + 2048);
    hipLaunchKernelGGL(k_beff_w, dim3(DIM_), dim3(64), 0, stream,
                       proj_w, conv_b, proj_b, alpha, beff);
    hipLaunchKernelGGL(k_weff_bf, dim3((DIM_ * F_) / 256), dim3(256), 0, stream,
                       proj_w, conv_w, alpha, Wt);
    hipLaunchKernelGGL(k_init, dim3((NROWS * DIM_ / 4) / 256), dim3(256), 0, stream,
                       beff, out);
    for (int q = 0; q < 9; ++q)
      hipLaunchKernelGGL(k_accq, dim3(128, 2), dim3(256), 0, stream,
                         x, emb, Wt, out, q);
    hipLaunchKernelGGL(k_ln, dim3(NROWS / 4), dim3(256), 0, stream,
                       gamma, beta, out);
  }
}